// Round 12
// baseline (1133.512 us; speedup 1.0000x reference)
//
#include <hip/hip_runtime.h>
#include <math.h>

// feat_gan loss on MI355X (gfx950) — lane-per-query restructure.
//
// Measured history:
//   r3  two-dispatch, wave-per-query:          110.25 µs total
//   r6  single-dispatch threadfence fusion:    223.6  µs (NEVER fuse: agent
//       fence = full XCD-L2 writeback on gfx950)
//   r9  wave-per-4-queries:                    113.7 µs; fg_fused = 42 µs,
//       VALUBusy 4%, HBM 3%, FETCH 9.9 MB -> latency-bound on the 64-way
//       scattered feature gather (lane c reads af[c*N+idx]: 64 lines/load).
//
// This version: LANE = QUERY. A wave owns 64 consecutive queries of one
// batch. Scan phase: all lanes walk the SAME src stream (wave-uniform
// broadcast loads, ~50 points expected = max of 64 geometric(0.081) first-
// hit indices), each lane predicated-captures its first hit index AND hit
// coordinates (xyz gather becomes free). Gather phase: loop rows c; lanes
// load af[c*N + ia_lane] -> same row, columns cluster in [0,64) => ~4 cache
// lines per load instead of 64. 4 waves/block redundantly scan and split
// the C rows into stripes (no barrier, no LDS). 320 blocks, 1280 partials.
//
// Shapes fixed by setup_inputs(): layer0 B=4,N=4096,C=64; layer1 B=4,N=1024,
// C=128. radius^2=1, nsample=1 (argmax-first). mask=false => exact 0
// contribution (reference zeroes both gathered groups); handled branchless
// via clamped index + 0/1 weight.

#define RAD2 1.0f

constexpr int B  = 4;
constexpr int N0 = 4096, C0 = 64;
constexpr int N1 = 1024, C1 = 128;
constexpr int QPG   = 64;               // queries per group (one per lane)
constexpr int SPLIT = 4;                // waves per group (row stripes)
constexpr int NG0 = B * N0 / QPG;       // 256 layer0 groups
constexpr int NG1 = B * N1 / QPG;       // 64 layer1 groups
constexpr int NGT = NG0 + NG1;          // 320 blocks
constexpr int NP0 = NG0 * SPLIT;        // 1024 layer0 partials
constexpr int NPT = NGT * SPLIT;        // 1280 partials

// Scan src stream for each lane's first point with d2 < RAD2 vs its query.
// All lanes read the same (wave-uniform) addresses; predicated capture of
// index and coordinates. Returns idx (-1 if none) and hit coords.
template<int N>
__device__ __forceinline__ int scan_first_hit(
    const float* __restrict__ src, float qx, float qy, float qz,
    float& hx, float& hy, float& hz)
{
    int idx = -1;
    hx = 0.0f; hy = 0.0f; hz = 0.0f;
    for (int m0 = 0; m0 < N; m0 += 8) {
        #pragma unroll
        for (int j = 0; j < 8; ++j) {
            const int m = m0 + j;
            const float sx = src[3 * m + 0];
            const float sy = src[3 * m + 1];
            const float sz = src[3 * m + 2];
            const float dx = qx - sx, dy = qy - sy, dz = qz - sz;
            if (idx < 0 && dx * dx + dy * dy + dz * dz < RAD2) {
                idx = m; hx = sx; hy = sy; hz = sz;
            }
        }
        if (__ballot(idx < 0) == 0ull) break;   // all lanes found their hit
    }
    return idx;
}

template<int C, int N>
__device__ __forceinline__ float group_loss(
    const float* __restrict__ aq,   // att_xyz, batch-local [N,3]
    const float* __restrict__ bq,   // bat_xyz, batch-local [N,3]
    const float* __restrict__ af,   // att_feat, batch-local [C,N]
    const float* __restrict__ bf,   // bat_feat, batch-local [C,N]
    int n0, int lane, int wid)
{
    // this lane's query point (coalesced across lanes)
    const int n = n0 + lane;
    const float qx = bq[3 * n + 0];
    const float qy = bq[3 * n + 1];
    const float qz = bq[3 * n + 2];

    // scan both streams; hit coords captured in registers (free xyz gather)
    float ahx, ahy, ahz, bhx, bhy, bhz;
    const int ia = scan_first_hit<N>(aq, qx, qy, qz, ahx, ahy, ahz);
    const int ib = scan_first_hit<N>(bq, qx, qy, qz, bhx, bhy, bhz);
    // ib is guaranteed >= 0 (self point m==n has d2 == 0 < 1)

    const float w   = (ia < 0) ? 0.0f : 1.0f;   // mask weight
    const int   iaC = (ia < 0) ? 0    : ia;     // clamped gather index

    float pq = 0.0f;
    if (wid == 0) {                 // xyz term counted once per query
        const float dx = ahx - bhx, dy = ahy - bhy, dz = ahz - bhz;
        pq = dx * dx + dy * dy + dz * dz;       // (ia<0 -> w=0 kills it)
    }

    // feature stripe: rows [wid*C/SPLIT, (wid+1)*C/SPLIT); per iteration
    // all lanes read the SAME row, columns cluster in [0,~64) -> few lines
    constexpr int STRIPE = C / SPLIT;
    const float* afr = af + (size_t)(wid * STRIPE) * N;
    const float* bfr = bf + (size_t)(wid * STRIPE) * N;
    #pragma unroll 8
    for (int c = 0; c < STRIPE; ++c) {
        const float d = afr[(size_t)c * N + iaC] - bfr[(size_t)c * N + ib];
        pq += d * d;
    }
    return w * pq;
}

__global__ __launch_bounds__(256) void fg_fused_kernel(
    const float* __restrict__ att_xyz0, const float* __restrict__ bat_xyz0,
    const float* __restrict__ att_feat0, const float* __restrict__ bat_feat0,
    const float* __restrict__ att_xyz1, const float* __restrict__ bat_xyz1,
    const float* __restrict__ att_feat1, const float* __restrict__ bat_feat1,
    double* __restrict__ partials)      // [NPT], one double per wave
{
    const int lane = threadIdx.x & 63;
    const int wid  = threadIdx.x >> 6;
    const int g    = blockIdx.x;

    float part;
    if (g < NG0) {                       // layer0: 64 groups per batch
        const int b  = g >> 6;
        const int n0 = (g & 63) * QPG;
        part = group_loss<C0, N0>(
            att_xyz0 + (size_t)b * N0 * 3, bat_xyz0 + (size_t)b * N0 * 3,
            att_feat0 + (size_t)b * C0 * N0, bat_feat0 + (size_t)b * C0 * N0,
            n0, lane, wid);
    } else {                             // layer1: 16 groups per batch
        const int gg = g - NG0;
        const int b  = gg >> 4;
        const int n0 = (gg & 15) * QPG;
        part = group_loss<C1, N1>(
            att_xyz1 + (size_t)b * N1 * 3, bat_xyz1 + (size_t)b * N1 * 3,
            att_feat1 + (size_t)b * C1 * N1, bat_feat1 + (size_t)b * C1 * N1,
            n0, lane, wid);
    }

    // wave reduce (64 lanes = 64 queries' stripe contributions)
    #pragma unroll
    for (int off = 32; off > 0; off >>= 1)
        part += __shfl_down(part, off);
    if (lane == 0) partials[g * SPLIT + wid] = (double)part;
}

__global__ __launch_bounds__(1024) void fg_finalize_kernel(
    const double* __restrict__ partials,
    float* __restrict__ out)
{
    const int t = threadIdx.x;
    double s0 = 0.0, s1 = 0.0;
    if (t < NP0) s0 = partials[t];                    // 1024 layer0 partials
    if (t < NPT - NP0) s1 = partials[NP0 + t];        // 256 layer1 partials

    #pragma unroll
    for (int off = 32; off > 0; off >>= 1) {
        s0 += __shfl_down(s0, off);
        s1 += __shfl_down(s1, off);
    }

    __shared__ double sh0[16], sh1[16];
    const int lane = t & 63, w = t >> 6;
    if (lane == 0) { sh0[w] = s0; sh1[w] = s1; }
    __syncthreads();
    if (t == 0) {
        double a0 = 0.0, a1 = 0.0;
        #pragma unroll
        for (int i = 0; i < 16; ++i) { a0 += sh0[i]; a1 += sh1[i]; }
        const double l0 = a0 * (1.0 / 1097728.0);   // 1/(4*4096*67)
        const double l1 = a1 * (1.0 / 536576.0);    // 1/(4*1024*131)
        double loss = 0.5 * (l0 + l1);
        if (isnan(loss)) loss = l1;   // reference: where(isnan, losses[-1], loss)
        out[0] = (float)loss;
    }
}

extern "C" void kernel_launch(void* const* d_in, const int* in_sizes, int n_in,
                              void* d_out, int out_size, void* d_ws, size_t ws_size,
                              hipStream_t stream) {
    // setup_inputs order:
    // 0 att_xyz0  1 att_xyz1  2 bat_xyz0  3 bat_xyz1
    // 4 att_feat0 5 att_feat1 6 bat_feat0 7 bat_feat1
    const float* att_xyz0  = (const float*)d_in[0];
    const float* att_xyz1  = (const float*)d_in[1];
    const float* bat_xyz0  = (const float*)d_in[2];
    const float* bat_xyz1  = (const float*)d_in[3];
    const float* att_feat0 = (const float*)d_in[4];
    const float* att_feat1 = (const float*)d_in[5];
    const float* bat_feat0 = (const float*)d_in[6];
    const float* bat_feat1 = (const float*)d_in[7];
    float* out = (float*)d_out;

    double* partials = (double*)d_ws;   // NPT doubles = 10 KiB scratch

    fg_fused_kernel<<<NGT, 256, 0, stream>>>(
        att_xyz0, bat_xyz0, att_feat0, bat_feat0,
        att_xyz1, bat_xyz1, att_feat1, bat_feat1, partials);

    fg_finalize_kernel<<<1, 1024, 0, stream>>>(partials, out);
}

// Round 16
// 107.799 us; speedup vs baseline: 10.5151x; 10.5151x over previous
//
#include <hip/hip_runtime.h>
#include <math.h>

// feat_gan loss on MI355X (gfx950) — register-scan hybrid.
//
// Measured history:
//   r3  wave-per-query, 2 dispatch:      110.25 µs (main kernel <40 µs)
//   r6  threadfence single-dispatch:     223.6  µs (agent fence = full L2 wb)
//   r9  wave-per-4-queries:              113.7  µs (main 42 µs, gather-scatter
//                                        latency-bound, FETCH 9.9 MB)
//   r12 lane-per-query serial scan:     1133.5  µs (main 1127 µs! ballot-break
//       never fires for tail queries: p(q)~1e-3 for |q|>3.5 -> ~full-N scans
//       at 1 point/iter/query. Scan must be 64-way per query.)
//
// This version keeps lane=query for the GATHER (row-wise coalesced, r12's one
// win) but scans wave-parallel:
//   Phase A: chunk-0 (64 pts) of att+bat in registers; 64 broadcast-ballot
//            rounds resolve ~90-95% of queries with zero memory traffic.
//   Phase B: pending queries (uniform bitmask) resolved collectively, 4
//            chunks (256 pts) per round -> full-N proof (mask=false or far
//            tail) = 16 rounds, not 64 (r9) / 4096 (r12).
// First-hit (argmax) semantics preserved: chunks tested in ascending index,
// ctz(ballot) = min index in chunk. mask=false => ia=-1 => weight 0 (exactly
// reproduces reference's zeroed groups). bat scan terminates by the chunk
// containing the query's own index (self d2=0).

#define RAD2 1.0f

constexpr int B  = 4;
constexpr int N0 = 4096, C0 = 64;
constexpr int N1 = 1024, C1 = 128;
constexpr int QPG   = 64;               // queries per group (one per lane)
constexpr int SPLIT = 4;                // waves per group (feature-row stripes)
constexpr int NG0 = B * N0 / QPG;       // 256 layer0 groups
constexpr int NG1 = B * N1 / QPG;       // 64 layer1 groups
constexpr int NGT = NG0 + NG1;          // 320 blocks
constexpr int NP0 = NG0 * SPLIT;        // 1024 layer0 partials
constexpr int NPT = NGT * SPLIT;        // 1280 partials

// Collective fallback: resolve pending queries' first hit in src[64..N) using
// 4-chunk (256-point) rounds. idx updated on the owning lane. pend is
// wave-uniform. Guarantees: tests chunks in ascending order; takes the first.
template<int N>
__device__ __forceinline__ void scan_tail(
    const float* __restrict__ src,
    float qx, float qy, float qz,          // per-lane query coords (lane=query)
    unsigned long long pend, int lane, int& idx)
{
    for (int m0 = 64; m0 < N && pend; m0 += 256) {
        float sx[4], sy[4], sz[4];
        bool  vld[4];
        #pragma unroll
        for (int k = 0; k < 4; ++k) {
            const int m  = m0 + (k << 6) + lane;
            const int mc = m < N ? m : N - 1;          // clamp address, mask test
            sx[k] = src[3 * mc + 0];
            sy[k] = src[3 * mc + 1];
            sz[k] = src[3 * mc + 2];
            vld[k] = m < N;
        }
        unsigned long long p = pend;
        while (p) {
            const int j = (int)__builtin_ctzll(p); p &= p - 1;
            const float qxj = __shfl(qx, j);
            const float qyj = __shfl(qy, j);
            const float qzj = __shfl(qz, j);
            int found = -1;
            #pragma unroll
            for (int k = 0; k < 4; ++k) {
                const float dx = qxj - sx[k], dy = qyj - sy[k], dz = qzj - sz[k];
                const unsigned long long h =
                    __ballot(vld[k] && dx * dx + dy * dy + dz * dz < RAD2);
                if (found < 0 && h) found = m0 + (k << 6) + (int)__builtin_ctzll(h);
            }
            if (found >= 0) {
                if (lane == j) idx = found;
                pend &= ~(1ull << j);
            }
        }
    }
}

template<int C, int N>
__device__ __forceinline__ float group_loss(
    const float* __restrict__ aq,   // att_xyz, batch-local [N,3]
    const float* __restrict__ bq,   // bat_xyz, batch-local [N,3]
    const float* __restrict__ af,   // att_feat, batch-local [C,N]
    const float* __restrict__ bf,   // bat_feat, batch-local [C,N]
    int n0, int lane, int wid)
{
    // this lane's query point (coalesced across lanes)
    const int n = n0 + lane;
    const float qx = bq[3 * n + 0];
    const float qy = bq[3 * n + 1];
    const float qz = bq[3 * n + 2];

    // chunk-0 source points of both streams, register-resident
    const float ax = aq[3 * lane + 0], ay = aq[3 * lane + 1], az = aq[3 * lane + 2];
    const float bx = bq[3 * lane + 0], by = bq[3 * lane + 1], bz = bq[3 * lane + 2];

    int ia = -1, ib = -1;                       // per-lane (lane=query) results
    unsigned long long pendA = 0ull, pendB = 0ull;   // wave-uniform miss masks

    // Phase A: 64 broadcast-ballot rounds, no memory traffic
    #pragma unroll
    for (int j = 0; j < 64; ++j) {
        const float qxj = __shfl(qx, j);
        const float qyj = __shfl(qy, j);
        const float qzj = __shfl(qz, j);
        const float dax = qxj - ax, day = qyj - ay, daz = qzj - az;
        const float dbx = qxj - bx, dby = qyj - by, dbz = qzj - bz;
        const unsigned long long hA = __ballot(dax * dax + day * day + daz * daz < RAD2);
        const unsigned long long hB = __ballot(dbx * dbx + dby * dby + dbz * dbz < RAD2);
        if (hA) { if (lane == j) ia = (int)__builtin_ctzll(hA); }
        else pendA |= (1ull << j);
        if (hB) { if (lane == j) ib = (int)__builtin_ctzll(hB); }
        else pendB |= (1ull << j);
    }

    // Phase B: collective tail scan for the few pending queries
    scan_tail<N>(aq, qx, qy, qz, pendA, lane, ia);
    scan_tail<N>(bq, qx, qy, qz, pendB, lane, ib);
    // ib >= 0 guaranteed (self point at index n has d2 == 0 < 1)

    const float w   = (ia < 0) ? 0.0f : 1.0f;   // mask weight
    const int   iaC = (ia < 0) ? 0    : ia;     // clamped gather index

    float pq = 0.0f;
    if (wid == 0) {                 // xyz term counted once per query
        const float dxx = aq[3 * iaC + 0] - bq[3 * ib + 0];
        const float dyy = aq[3 * iaC + 1] - bq[3 * ib + 1];
        const float dzz = aq[3 * iaC + 2] - bq[3 * ib + 2];
        pq = dxx * dxx + dyy * dyy + dzz * dzz;
    }

    // feature stripe: rows [wid*C/SPLIT, (wid+1)*C/SPLIT); per iteration all
    // lanes read the SAME row, columns cluster in [0,~64) -> few cache lines
    constexpr int STRIPE = C / SPLIT;
    const float* afr = af + (size_t)(wid * STRIPE) * N;
    const float* bfr = bf + (size_t)(wid * STRIPE) * N;
    #pragma unroll 8
    for (int c = 0; c < STRIPE; ++c) {
        const float d = afr[(size_t)c * N + iaC] - bfr[(size_t)c * N + ib];
        pq += d * d;
    }
    return w * pq;
}

__global__ __launch_bounds__(256) void fg_fused_kernel(
    const float* __restrict__ att_xyz0, const float* __restrict__ bat_xyz0,
    const float* __restrict__ att_feat0, const float* __restrict__ bat_feat0,
    const float* __restrict__ att_xyz1, const float* __restrict__ bat_xyz1,
    const float* __restrict__ att_feat1, const float* __restrict__ bat_feat1,
    double* __restrict__ partials)      // [NPT], one double per wave
{
    const int lane = threadIdx.x & 63;
    const int wid  = threadIdx.x >> 6;
    const int g    = blockIdx.x;

    float part;
    if (g < NG0) {                       // layer0: 64 groups per batch
        const int b  = g >> 6;
        const int n0 = (g & 63) * QPG;
        part = group_loss<C0, N0>(
            att_xyz0 + (size_t)b * N0 * 3, bat_xyz0 + (size_t)b * N0 * 3,
            att_feat0 + (size_t)b * C0 * N0, bat_feat0 + (size_t)b * C0 * N0,
            n0, lane, wid);
    } else {                             // layer1: 16 groups per batch
        const int gg = g - NG0;
        const int b  = gg >> 4;
        const int n0 = (gg & 15) * QPG;
        part = group_loss<C1, N1>(
            att_xyz1 + (size_t)b * N1 * 3, bat_xyz1 + (size_t)b * N1 * 3,
            att_feat1 + (size_t)b * C1 * N1, bat_feat1 + (size_t)b * C1 * N1,
            n0, lane, wid);
    }

    // wave reduce (64 lanes = 64 queries' stripe contributions)
    #pragma unroll
    for (int off = 32; off > 0; off >>= 1)
        part += __shfl_down(part, off);
    if (lane == 0) partials[g * SPLIT + wid] = (double)part;
}

__global__ __launch_bounds__(1024) void fg_finalize_kernel(
    const double* __restrict__ partials,
    float* __restrict__ out)
{
    const int t = threadIdx.x;
    double s0 = 0.0, s1 = 0.0;
    if (t < NP0) s0 = partials[t];                    // 1024 layer0 partials
    if (t < NPT - NP0) s1 = partials[NP0 + t];        // 256 layer1 partials

    #pragma unroll
    for (int off = 32; off > 0; off >>= 1) {
        s0 += __shfl_down(s0, off);
        s1 += __shfl_down(s1, off);
    }

    __shared__ double sh0[16], sh1[16];
    const int lane = t & 63, w = t >> 6;
    if (lane == 0) { sh0[w] = s0; sh1[w] = s1; }
    __syncthreads();
    if (t == 0) {
        double a0 = 0.0, a1 = 0.0;
        #pragma unroll
        for (int i = 0; i < 16; ++i) { a0 += sh0[i]; a1 += sh1[i]; }
        const double l0 = a0 * (1.0 / 1097728.0);   // 1/(4*4096*67)
        const double l1 = a1 * (1.0 / 536576.0);    // 1/(4*1024*131)
        double loss = 0.5 * (l0 + l1);
        if (isnan(loss)) loss = l1;   // reference: where(isnan, losses[-1], loss)
        out[0] = (float)loss;
    }
}

extern "C" void kernel_launch(void* const* d_in, const int* in_sizes, int n_in,
                              void* d_out, int out_size, void* d_ws, size_t ws_size,
                              hipStream_t stream) {
    // setup_inputs order:
    // 0 att_xyz0  1 att_xyz1  2 bat_xyz0  3 bat_xyz1
    // 4 att_feat0 5 att_feat1 6 bat_feat0 7 bat_feat1
    const float* att_xyz0  = (const float*)d_in[0];
    const float* att_xyz1  = (const float*)d_in[1];
    const float* bat_xyz0  = (const float*)d_in[2];
    const float* bat_xyz1  = (const float*)d_in[3];
    const float* att_feat0 = (const float*)d_in[4];
    const float* att_feat1 = (const float*)d_in[5];
    const float* bat_feat0 = (const float*)d_in[6];
    const float* bat_feat1 = (const float*)d_in[7];
    float* out = (float*)d_out;

    double* partials = (double*)d_ws;   // NPT doubles = 10 KiB scratch

    fg_fused_kernel<<<NGT, 256, 0, stream>>>(
        att_xyz0, bat_xyz0, att_feat0, bat_feat0,
        att_xyz1, bat_xyz1, att_feat1, bat_feat1, partials);

    fg_finalize_kernel<<<1, 1024, 0, stream>>>(partials, out);
}